// Round 10
// baseline (100.433 us; speedup 1.0000x reference)
//
#include <hip/hip_runtime.h>
#include <cstdint>

#define BB 16
#define NN 25200
#define NCLS 80
#define NF (5 + NCLS)
#define MAXDET 300
#define MTGT 50
#define CONF 0.8f
#define NMSTH 0.4f
#define WORDS 10
#define NBINS 2048
#define SBUF 2048
#define APB 64                              // anchors per block in k_score
#define CHUNK_V4 (APB * NF / 4)             // 1360 float4 per block
#define SCORE_BLOCKS ((BB * NN) / APB)      // 6300
#define NTGT_BLOCKS ((BB * MTGT + 127) / 128)
#define HSTRIDE 33                          // hist row stride (bank de-alias)

// workspace byte offsets
#define WS_SCORE 0
#define WS_DS   ((size_t)BB * NN * 4)
#define WS_DI   (WS_DS + (size_t)BB * MAXDET * 4)
#define WS_GBOX (WS_DI + (size_t)BB * MAXDET * 4)
#define WS_GLAB (WS_GBOX + (size_t)BB * MAXDET * 16)
#define WS_SUPP (WS_GLAB + (size_t)BB * MAXDET * 4)

// output float offsets (return order: pb, ps, pl, pv, tb, ts, tl, tv)
#define O_PB 0
#define O_PS (BB * MAXDET * 4)
#define O_PL (O_PS + BB * MAXDET)
#define O_PV (O_PL + BB * MAXDET)
#define O_TB (O_PV + BB * MAXDET)
#define O_TS (O_TB + BB * MTGT * 4)
#define O_TL (O_TS + BB * MTGT)
#define O_TV (O_TL + BB * MTGT)

// 128-thread block stages 64 rows (21.76 KB -> 7 blocks/CU) via async
// global_load_lds width=16 (no VGPR round-trip). Scan: 2 threads/anchor
// (banks 21a+8h mod 32 = exact 2-way = free), 4 max accumulators (max is
// order-independent -> bit-exact), one shfl_xor, single f32 mul.
// Measured ~21 us ~= 137MB / 6.3TB/s -> at HBM roofline. Tail blocks: targets.
__global__ __launch_bounds__(128) void k_score(const float* __restrict__ preds,
                                               float* __restrict__ scores,
                                               const float* __restrict__ tt,
                                               const int* __restrict__ len,
                                               float* __restrict__ out) {
    __shared__ float st[APB * NF];          // 21760 B
    int tid = threadIdx.x;
    int bid = blockIdx.x;

    if (bid >= SCORE_BLOCKS) {              // fused target transform
        int t = (bid - SCORE_BLOCKS) * 128 + tid;
        if (t < BB * MTGT) {
            int b = t / MTGT, m = t - b * MTGT;
            const float* row = tt + (size_t)t * 6;
            bool valid = m < len[b];
            float cx = row[0], cy = row[1], w = row[2], h = row[3];
            float x1 = cx - 0.5f * w, y1 = cy - 0.5f * h;
            float* tb = out + O_TB + (size_t)t * 4;
            tb[0] = valid ? x1 : 0.f;
            tb[1] = valid ? y1 : 0.f;
            tb[2] = valid ? (x1 + w) : 0.f;
            tb[3] = valid ? (y1 + h) : 0.f;
            out[O_TS + t] = valid ? row[4] : 0.f;
            out[O_TL + t] = valid ? (float)(int)row[5] : -1.f;
            out[O_TV + t] = valid ? 1.f : 0.f;
        }
        return;
    }

    int w = tid >> 6;                       // wave id (uniform per wave)
    const float4* src = (const float4*)(preds + (size_t)bid * (APB * NF));
    #pragma unroll
    for (int i = 0; i < 11; ++i) {
        int idx = i * 128 + tid;            // global float4 index, contiguous
        if (idx < CHUNK_V4) {
            // LDS dest: wave-uniform base; HW scatters lane l at base + l*16.
            __builtin_amdgcn_global_load_lds(
                (const __attribute__((address_space(1))) void*)(src + idx),
                (__attribute__((address_space(3))) void*)(st + (i * 128 + w * 64) * 4),
                16, 0, 0);
        }
    }
    __syncthreads();                        // drains vmcnt -> LDS valid

    int a = tid >> 1, h = tid & 1;          // anchor, half
    const float* cls = st + a * NF + 5 + h * 40;
    float m0 = cls[0], m1 = cls[1], m2 = cls[2], m3 = cls[3];
    #pragma unroll
    for (int f = 4; f < 40; f += 4) {
        m0 = fmaxf(m0, cls[f]);     m1 = fmaxf(m1, cls[f + 1]);
        m2 = fmaxf(m2, cls[f + 2]); m3 = fmaxf(m3, cls[f + 3]);
    }
    float m = fmaxf(fmaxf(m0, m1), fmaxf(m2, m3));
    m = fmaxf(m, __shfl_xor(m, 1));
    if (h == 0) scores[bid * APB + a] = st[a * NF + 4] * m;  // single mul, bit-exact
}

// One block per batch: histogram select + PROVEN bitonic-512 sort (rank-by-
// counting reverted: its serial LDS-latency chain cost ~35+ us, R9 post-mortem).
// Coarse bins only SELECT (cut-bin ties all included); the 64-bit key sort
// ORDERS -> bit-identical to full sort (JAX top_k ties via inverted index).
__global__ __launch_bounds__(1024) void k_select(const float* __restrict__ scores,
                                                 float* __restrict__ dscore,
                                                 unsigned* __restrict__ didx) {
    __shared__ int hist[64 * HSTRIDE];      // superbin-major, stride 33: bank-clean
    __shared__ unsigned long long sk[SBUF];
    __shared__ int lcnt;
    __shared__ int scut;
    int b = blockIdx.x;
    int tid = threadIdx.x;
    int lane = tid & 63;

    if (tid == 0) lcnt = 0;
    for (int i = tid; i < 64 * HSTRIDE; i += 1024) hist[i] = 0;
    for (int i = tid; i < SBUF; i += 1024) sk[i] = 0ull;   // pad keys for sort
    __syncthreads();

    // phase A: histogram of candidate score bits. scores in (0.8,1.0] share one
    // exponent region -> (u - 0x3F400000)>>12 is monotone in float order.
    for (int i = tid; i < NN; i += 1024) {
        float s = scores[b * NN + i];
        if (s > CONF) {
            unsigned u = __float_as_uint(s);
            int bin = (int)((u - 0x3F400000u) >> 12);
            bin = bin < 0 ? 0 : (bin > NBINS - 1 ? NBINS - 1 : bin);
            atomicAdd(&hist[(bin >> 5) * HSTRIDE + (bin & 31)], 1);
        }
    }
    __syncthreads();

    // phase B: find cut bin (largest bin with suffix-count >= 300), one wave
    if (tid < 64) {
        int sb = 0;
        #pragma unroll
        for (int k = 0; k < 32; ++k) sb += hist[lane * HSTRIDE + k];  // banks clean
        int cum = sb;                              // suffix sum over 64 superbins
        #pragma unroll
        for (int d = 1; d < 64; d <<= 1) {
            int o = __shfl_down(cum, d);
            if (lane + d < 64) cum += o;
        }
        unsigned long long m = __ballot(cum >= MAXDET);
        int cutbin = 0;
        if (m) {
            int cutS = 63 - __clzll(m);
            int tail = (cutS < 63) ? __shfl(cum, cutS + 1) : 0;
            int hh = (lane < 32) ? hist[cutS * HSTRIDE + lane] : 0;
            int c2 = hh;                           // suffix sum within superbin
            #pragma unroll
            for (int d = 1; d < 32; d <<= 1) {
                int o = __shfl_down(c2, d);
                if (lane + d < 32) c2 += o;
            }
            c2 += tail;
            unsigned long long m2 = __ballot(lane < 32 && c2 >= MAXDET);
            int cutL = 63 - __clzll(m2);           // m2 != 0 guaranteed
            cutbin = cutS * 32 + cutL;
        }
        if (lane == 0) scut = cutbin;
    }
    __syncthreads();
    int cutbin = scut;

    // phase C: compact bin >= cutbin (wave-aggregated LDS atomic)
    for (int i = tid; i < ((NN + 1023) & ~1023); i += 1024) {
        float s = 0.f; bool pass = false;
        if (i < NN) {
            s = scores[b * NN + i];
            if (s > CONF) {
                unsigned u = __float_as_uint(s);
                int bin = (int)((u - 0x3F400000u) >> 12);
                bin = bin < 0 ? 0 : (bin > NBINS - 1 ? NBINS - 1 : bin);
                pass = bin >= cutbin;
            }
        }
        unsigned long long mask = __ballot(pass);
        int wcnt = __popcll(mask);
        int bs = 0;
        if (lane == 0 && wcnt) bs = atomicAdd(&lcnt, wcnt);
        bs = __shfl(bs, 0);
        if (pass) {
            int pos = bs + __popcll(mask & ((1ull << lane) - 1ull));
            if (pos < SBUF)
                sk[pos] = ((unsigned long long)__float_as_uint(s) << 32) |
                          (unsigned long long)(0xFFFFFFFFu - (unsigned)i);
        }
    }
    __syncthreads();

    // phase D: bitonic sort P in {512,1024,2048} elements, descending (proven)
    int M = lcnt; if (M > SBUF) M = SBUF;
    unsigned P = 512;
    while ((int)P < M) P <<= 1;

    for (unsigned k = 2; k <= P; k <<= 1) {
        for (unsigned j = k >> 1; j > 0; j >>= 1) {
            __syncthreads();
            for (unsigned i = tid; i < P; i += 1024) {
                unsigned ixj = i ^ j;
                if (ixj > i) {
                    unsigned long long a = sk[i], d = sk[ixj];
                    bool desc = ((i & k) == 0);
                    if (desc ? (a < d) : (a > d)) { sk[i] = d; sk[ixj] = a; }
                }
            }
        }
    }
    __syncthreads();
    for (int q = tid; q < MAXDET; q += 1024) {
        unsigned long long key = sk[q];
        unsigned sbits = (unsigned)(key >> 32);
        dscore[b * MAXDET + q] = __uint_as_float(sbits);
        didx[b * MAXDET + q]   = sbits ? (0xFFFFFFFFu - (unsigned)(key & 0xFFFFFFFFu)) : 0u;
    }
}

// wave per detection: gather row, first-occurrence argmax, box -> gbox/glabel
__global__ __launch_bounds__(512) void k_gather(const float* __restrict__ preds,
                                                const float* __restrict__ dscore,
                                                const unsigned* __restrict__ didx,
                                                float* __restrict__ gbox,
                                                int* __restrict__ glabel) {
    int g    = blockIdx.x * 8 + (threadIdx.x >> 6);   // b*MAXDET + k
    int lane = threadIdx.x & 63;
    float sc = dscore[g];
    if (sc > 0.f) {
        int b = g / MAXDET;
        int idx = (int)didx[g];
        const float* row = preds + ((size_t)b * NN + (size_t)idx) * NF;
        float v = row[5 + lane]; int ci = lane;
        if (lane < 16) { float v2 = row[69 + lane]; if (v2 > v) { v = v2; ci = lane + 64; } }
        #pragma unroll
        for (int m = 32; m >= 1; m >>= 1) {
            float ov = __shfl_xor(v, m);
            int   oi = __shfl_xor(ci, m);
            if (ov > v || (ov == v && oi < ci)) { v = ov; ci = oi; }
        }
        if (lane == 0) {
            float cx = row[0], cy = row[1], w = row[2], h = row[3];
            float x1 = cx - 0.5f * w, y1 = cy - 0.5f * h;   // 0.5*w exact -> fma-safe
            float4 bx = { x1, y1, x1 + w, y1 + h };
            ((float4*)gbox)[g] = bx;
            glabel[g] = ci;
        }
    } else if (lane == 0) {
        float4 zz = { 0.f, 0.f, 0.f, 0.f };
        ((float4*)gbox)[g] = zz;
        glabel[g] = -1;
    }
}

// thread per 32-bit suppression word: 32 serial IoUs, no atomics, each word
// written once. IoU op-order matches reference; _rn blocks fma-contract.
__global__ __launch_bounds__(256) void k_mask(const float* __restrict__ gbox,
                                              const int* __restrict__ glabel,
                                              const float* __restrict__ dscore,
                                              unsigned* __restrict__ gsupp) {
    int T = blockIdx.x * 256 + threadIdx.x;
    if (T >= BB * MAXDET * WORDS) return;
    int g  = T / WORDS;                    // b*MAXDET + i
    int jw = T - g * WORDS;
    int b  = g / MAXDET;
    int i  = g - b * MAXDET;

    unsigned word = 0;
    int jbase = jw * 32;
    if (jbase + 31 > i) {                  // word has some j > i
        float4 bi = ((const float4*)gbox)[g];
        int   li = glabel[g];
        float si = dscore[g];
        float ai = __fmul_rn(fmaxf(__fsub_rn(bi.z, bi.x), 0.f),
                             fmaxf(__fsub_rn(bi.w, bi.y), 0.f));
        #pragma unroll 4
        for (int t = 0; t < 32; ++t) {
            int j = jbase + t;
            if (j > i && j < MAXDET) {
                int gj = b * MAXDET + j;
                if (glabel[gj] == li && si > 0.f && dscore[gj] > 0.f) {
                    float4 bj = ((const float4*)gbox)[gj];
                    float xx1 = fmaxf(bi.x, bj.x);
                    float yy1 = fmaxf(bi.y, bj.y);
                    float xx2 = fminf(bi.z, bj.z);
                    float yy2 = fminf(bi.w, bj.w);
                    float iw = fmaxf(__fsub_rn(xx2, xx1), 0.f);
                    float ih = fmaxf(__fsub_rn(yy2, yy1), 0.f);
                    float inter = __fmul_rn(iw, ih);
                    float aj = __fmul_rn(fmaxf(__fsub_rn(bj.z, bj.x), 0.f),
                                         fmaxf(__fsub_rn(bj.w, bj.y), 0.f));
                    float den = __fadd_rn(__fsub_rn(__fadd_rn(ai, aj), inter), 1e-9f);
                    float iou = inter / den;     // exact IEEE div (no fast-math)
                    if (iou > NMSTH) word |= 1u << t;
                }
            }
        }
    }
    gsupp[T] = word;
}

// one wave per batch: register-resident keep + nonzero-row summary; LDS touched
// only on actual suppressions. Fused output write (single wave -> no syncs).
__global__ __launch_bounds__(64) void k_greedy(const float* __restrict__ gbox,
                                               const int* __restrict__ glabel,
                                               const float* __restrict__ dscore,
                                               const unsigned* __restrict__ gsupp,
                                               float* __restrict__ out) {
    __shared__ unsigned ls[MAXDET * WORDS];
    int b = blockIdx.x;
    int lane = threadIdx.x;

    for (int w = lane; w < MAXDET * WORDS; w += 64)
        ls[w] = gsupp[b * MAXDET * WORDS + w];
    __syncthreads();

    unsigned keep = 0, nzm = 0;
    #pragma unroll
    for (int s = 0; s < 5; ++s) {
        int k = s * 64 + lane;
        bool kb = (k < MAXDET) && (dscore[b * MAXDET + k] > 0.f);
        unsigned long long m = __ballot(kb);
        if (lane == 2 * s)     keep = (unsigned)m;
        if (lane == 2 * s + 1) keep = (unsigned)(m >> 32);
        unsigned nz = 0;
        if (k < MAXDET) {
            #pragma unroll
            for (int w = 0; w < WORDS; ++w) nz |= ls[k * WORDS + w];
        }
        unsigned long long mn = __ballot(nz != 0u);
        if (lane == 2 * s)     nzm = (unsigned)mn;
        if (lane == 2 * s + 1) nzm = (unsigned)(mn >> 32);
    }

    for (int i = 0; i < MAXDET; ++i) {
        int idx = i >> 5;                       // uniform
        unsigned kw = __shfl(keep, idx);
        unsigned nw = __shfl(nzm, idx);
        if (((kw & nw) >> (i & 31)) & 1u) {
            if (lane < WORDS) keep &= ~ls[i * WORDS + lane];
        }
    }

    #pragma unroll
    for (int s = 0; s < 5; ++s) {
        int k = s * 64 + lane;
        if (k < MAXDET) {
            unsigned kw = __shfl(keep, k >> 5);
            bool kp = (kw >> (k & 31)) & 1u;
            int g = b * MAXDET + k;
            float4 bx = ((const float4*)gbox)[g];
            float4 zz = { 0.f, 0.f, 0.f, 0.f };
            ((float4*)(out + O_PB))[g] = kp ? bx : zz;
            out[O_PS + g] = kp ? dscore[g] : 0.f;
            out[O_PL + g] = kp ? (float)glabel[g] : -1.f;
            out[O_PV + g] = kp ? 1.f : 0.f;
        }
    }
}

extern "C" void kernel_launch(void* const* d_in, const int* in_sizes, int n_in,
                              void* d_out, int out_size, void* d_ws, size_t ws_size,
                              hipStream_t stream) {
    const float* preds = (const float*)d_in[0];
    const float* tt    = (const float*)d_in[1];
    const int*   len   = (const int*)d_in[2];
    float* out = (float*)d_out;

    char* ws = (char*)d_ws;
    float*    scores = (float*)(ws + WS_SCORE);
    float*    dscore = (float*)(ws + WS_DS);
    unsigned* didx   = (unsigned*)(ws + WS_DI);
    float*    gbox   = (float*)(ws + WS_GBOX);
    int*      glabel = (int*)(ws + WS_GLAB);
    unsigned* gsupp  = (unsigned*)(ws + WS_SUPP);

    k_score <<<SCORE_BLOCKS + NTGT_BLOCKS, 128, 0, stream>>>(preds, scores, tt, len, out);
    k_select<<<BB, 1024, 0, stream>>>(scores, dscore, didx);
    k_gather<<<(BB * MAXDET) / 8, 512, 0, stream>>>(preds, dscore, didx, gbox, glabel);
    k_mask  <<<(BB * MAXDET * WORDS + 255) / 256, 256, 0, stream>>>(gbox, glabel, dscore, gsupp);
    k_greedy<<<BB, 64, 0, stream>>>(gbox, glabel, dscore, gsupp, out);
}

// Round 11
// 90.185 us; speedup vs baseline: 1.1136x; 1.1136x over previous
//
#include <hip/hip_runtime.h>
#include <cstdint>

#define BB 16
#define NN 25200
#define NCLS 80
#define NF (5 + NCLS)
#define MAXDET 300
#define MTGT 50
#define CONF 0.8f
#define NMSTH 0.4f
#define WORDS 10
#define NBINS 2048
#define SBUF 2048
#define APB 64                              // anchors per block in k_score
#define CHUNK_V4 (APB * NF / 4)             // 1360 float4 per block
#define SCORE_BLOCKS ((BB * NN) / APB)      // 6300
#define NTGT_BLOCKS ((BB * MTGT + 127) / 128)
#define HSTRIDE 33                          // hist row stride (bank de-alias)

// workspace byte offsets
#define WS_SCORE 0
#define WS_DS   ((size_t)BB * NN * 4)
#define WS_DI   (WS_DS + (size_t)BB * MAXDET * 4)
#define WS_GBOX (WS_DI + (size_t)BB * MAXDET * 4)
#define WS_GLAB (WS_GBOX + (size_t)BB * MAXDET * 16)

// output float offsets (return order: pb, ps, pl, pv, tb, ts, tl, tv)
#define O_PB 0
#define O_PS (BB * MAXDET * 4)
#define O_PL (O_PS + BB * MAXDET)
#define O_PV (O_PL + BB * MAXDET)
#define O_TB (O_PV + BB * MAXDET)
#define O_TS (O_TB + BB * MTGT * 4)
#define O_TL (O_TS + BB * MTGT)
#define O_TV (O_TL + BB * MTGT)

// 128-thread block stages 64 rows (21.76 KB -> 7 blocks/CU) via async
// global_load_lds width=16. Scan: 2 threads/anchor (2-way bank = free), 4 max
// accumulators (order-independent -> bit-exact), one shfl_xor, single f32 mul.
// Measured ~21-24 us ~= 137MB / 6.3TB/s -> HBM roofline. Tail blocks: targets.
__global__ __launch_bounds__(128) void k_score(const float* __restrict__ preds,
                                               float* __restrict__ scores,
                                               const float* __restrict__ tt,
                                               const int* __restrict__ len,
                                               float* __restrict__ out) {
    __shared__ float st[APB * NF];          // 21760 B
    int tid = threadIdx.x;
    int bid = blockIdx.x;

    if (bid >= SCORE_BLOCKS) {              // fused target transform
        int t = (bid - SCORE_BLOCKS) * 128 + tid;
        if (t < BB * MTGT) {
            int b = t / MTGT, m = t - b * MTGT;
            const float* row = tt + (size_t)t * 6;
            bool valid = m < len[b];
            float cx = row[0], cy = row[1], w = row[2], h = row[3];
            float x1 = cx - 0.5f * w, y1 = cy - 0.5f * h;
            float* tb = out + O_TB + (size_t)t * 4;
            tb[0] = valid ? x1 : 0.f;
            tb[1] = valid ? y1 : 0.f;
            tb[2] = valid ? (x1 + w) : 0.f;
            tb[3] = valid ? (y1 + h) : 0.f;
            out[O_TS + t] = valid ? row[4] : 0.f;
            out[O_TL + t] = valid ? (float)(int)row[5] : -1.f;
            out[O_TV + t] = valid ? 1.f : 0.f;
        }
        return;
    }

    int w = tid >> 6;                       // wave id (uniform per wave)
    const float4* src = (const float4*)(preds + (size_t)bid * (APB * NF));
    #pragma unroll
    for (int i = 0; i < 11; ++i) {
        int idx = i * 128 + tid;            // global float4 index, contiguous
        if (idx < CHUNK_V4) {
            __builtin_amdgcn_global_load_lds(
                (const __attribute__((address_space(1))) void*)(src + idx),
                (__attribute__((address_space(3))) void*)(st + (i * 128 + w * 64) * 4),
                16, 0, 0);
        }
    }
    __syncthreads();                        // drains vmcnt -> LDS valid

    int a = tid >> 1, h = tid & 1;          // anchor, half
    const float* cls = st + a * NF + 5 + h * 40;
    float m0 = cls[0], m1 = cls[1], m2 = cls[2], m3 = cls[3];
    #pragma unroll
    for (int f = 4; f < 40; f += 4) {
        m0 = fmaxf(m0, cls[f]);     m1 = fmaxf(m1, cls[f + 1]);
        m2 = fmaxf(m2, cls[f + 2]); m3 = fmaxf(m3, cls[f + 3]);
    }
    float m = fmaxf(fmaxf(m0, m1), fmaxf(m2, m3));
    m = fmaxf(m, __shfl_xor(m, 1));
    if (h == 0) scores[bid * APB + a] = st[a * NF + 4] * m;  // single mul, bit-exact
}

// One block per batch. FIX (R10 post-mortem): the two 25-iteration global-scan
// chains (~15us each, per-wave latency-serial) are replaced by ONE async LDS
// staging of the whole 100.8KB score row; hist/compact then read LDS. Coarse
// bins only SELECT (cut-bin ties all included); bitonic-512 on 64-bit keys
// ORDERS -> bit-identical to full sort (JAX top_k ties via inverted index).
__global__ __launch_bounds__(1024) void k_select(const float* __restrict__ scores,
                                                 float* __restrict__ dscore,
                                                 unsigned* __restrict__ didx) {
    __shared__ float sc[NN];                // 100800 B
    __shared__ int hist[64 * HSTRIDE];      // 8448 B, superbin-major stride 33
    __shared__ unsigned long long sk[SBUF]; // 16384 B   (total ~125.6 KB)
    __shared__ int lcnt;
    __shared__ int scut;
    int b = blockIdx.x;
    int tid = threadIdx.x;
    int lane = tid & 63;
    int w = tid >> 6;

    if (tid == 0) lcnt = 0;
    for (int i = tid; i < 64 * HSTRIDE; i += 1024) hist[i] = 0;
    for (int i = tid; i < SBUF; i += 1024) sk[i] = 0ull;   // pad keys for sort

    // stage scores[b] -> LDS via async global_load_lds width=16
    // (base byte offset b*100800 is 16B-aligned; tail wave partially masked)
    const float4* src = (const float4*)(scores + (size_t)b * NN);
    #pragma unroll
    for (int i = 0; i < 7; ++i) {
        int idx = i * 1024 + tid;           // float4 index, 6300 total
        if (idx < NN / 4) {
            __builtin_amdgcn_global_load_lds(
                (const __attribute__((address_space(1))) void*)(src + idx),
                (__attribute__((address_space(3))) void*)(sc + (i * 1024 + w * 64) * 4),
                16, 0, 0);
        }
    }
    __syncthreads();                        // drains vmcnt -> sc valid

    // phase A: histogram from LDS. scores in (0.8,1.0] share one exponent
    // region -> (u - 0x3F400000)>>12 is monotone in float order.
    for (int i = tid; i < NN; i += 1024) {
        float s = sc[i];
        if (s > CONF) {
            unsigned u = __float_as_uint(s);
            int bin = (int)((u - 0x3F400000u) >> 12);
            bin = bin < 0 ? 0 : (bin > NBINS - 1 ? NBINS - 1 : bin);
            atomicAdd(&hist[(bin >> 5) * HSTRIDE + (bin & 31)], 1);
        }
    }
    __syncthreads();

    // phase B: find cut bin (largest bin with suffix-count >= 300), one wave
    if (tid < 64) {
        int sb = 0;
        #pragma unroll
        for (int k = 0; k < 32; ++k) sb += hist[lane * HSTRIDE + k];
        int cum = sb;                              // suffix sum over 64 superbins
        #pragma unroll
        for (int d = 1; d < 64; d <<= 1) {
            int o = __shfl_down(cum, d);
            if (lane + d < 64) cum += o;
        }
        unsigned long long m = __ballot(cum >= MAXDET);
        int cutbin = 0;
        if (m) {
            int cutS = 63 - __clzll(m);
            int tail = (cutS < 63) ? __shfl(cum, cutS + 1) : 0;
            int hh = (lane < 32) ? hist[cutS * HSTRIDE + lane] : 0;
            int c2 = hh;                           // suffix sum within superbin
            #pragma unroll
            for (int d = 1; d < 32; d <<= 1) {
                int o = __shfl_down(c2, d);
                if (lane + d < 32) c2 += o;
            }
            c2 += tail;
            unsigned long long m2 = __ballot(lane < 32 && c2 >= MAXDET);
            int cutL = 63 - __clzll(m2);           // m2 != 0 guaranteed
            cutbin = cutS * 32 + cutL;
        }
        if (lane == 0) scut = cutbin;
    }
    __syncthreads();
    int cutbin = scut;

    // phase C: compact bin >= cutbin from LDS (wave-aggregated LDS atomic)
    for (int i = tid; i < ((NN + 1023) & ~1023); i += 1024) {
        float s = 0.f; bool pass = false;
        if (i < NN) {
            s = sc[i];
            if (s > CONF) {
                unsigned u = __float_as_uint(s);
                int bin = (int)((u - 0x3F400000u) >> 12);
                bin = bin < 0 ? 0 : (bin > NBINS - 1 ? NBINS - 1 : bin);
                pass = bin >= cutbin;
            }
        }
        unsigned long long mask = __ballot(pass);
        int wcnt = __popcll(mask);
        int bs = 0;
        if (lane == 0 && wcnt) bs = atomicAdd(&lcnt, wcnt);
        bs = __shfl(bs, 0);
        if (pass) {
            int pos = bs + __popcll(mask & ((1ull << lane) - 1ull));
            if (pos < SBUF)
                sk[pos] = ((unsigned long long)__float_as_uint(s) << 32) |
                          (unsigned long long)(0xFFFFFFFFu - (unsigned)i);
        }
    }
    __syncthreads();

    // phase D: bitonic sort P in {512,1024,2048} elements, descending (proven)
    int M = lcnt; if (M > SBUF) M = SBUF;
    unsigned P = 512;
    while ((int)P < M) P <<= 1;

    for (unsigned k = 2; k <= P; k <<= 1) {
        for (unsigned j = k >> 1; j > 0; j >>= 1) {
            __syncthreads();
            for (unsigned i = tid; i < P; i += 1024) {
                unsigned ixj = i ^ j;
                if (ixj > i) {
                    unsigned long long a = sk[i], d = sk[ixj];
                    bool desc = ((i & k) == 0);
                    if (desc ? (a < d) : (a > d)) { sk[i] = d; sk[ixj] = a; }
                }
            }
        }
    }
    __syncthreads();
    for (int q = tid; q < MAXDET; q += 1024) {
        unsigned long long key = sk[q];
        unsigned sbits = (unsigned)(key >> 32);
        dscore[b * MAXDET + q] = __uint_as_float(sbits);
        didx[b * MAXDET + q]   = sbits ? (0xFFFFFFFFu - (unsigned)(key & 0xFFFFFFFFu)) : 0u;
    }
}

// wave per detection (600 blocks -> all rows fetched in parallel): gather row,
// first-occurrence argmax, box -> gbox/glabel
__global__ __launch_bounds__(512) void k_gather(const float* __restrict__ preds,
                                                const float* __restrict__ dscore,
                                                const unsigned* __restrict__ didx,
                                                float* __restrict__ gbox,
                                                int* __restrict__ glabel) {
    int g    = blockIdx.x * 8 + (threadIdx.x >> 6);   // b*MAXDET + k
    int lane = threadIdx.x & 63;
    float sc = dscore[g];
    if (sc > 0.f) {
        int b = g / MAXDET;
        int idx = (int)didx[g];
        const float* row = preds + ((size_t)b * NN + (size_t)idx) * NF;
        float v = row[5 + lane]; int ci = lane;
        if (lane < 16) { float v2 = row[69 + lane]; if (v2 > v) { v = v2; ci = lane + 64; } }
        #pragma unroll
        for (int m = 32; m >= 1; m >>= 1) {
            float ov = __shfl_xor(v, m);
            int   oi = __shfl_xor(ci, m);
            if (ov > v || (ov == v && oi < ci)) { v = ov; ci = oi; }
        }
        if (lane == 0) {
            float cx = row[0], cy = row[1], w = row[2], h = row[3];
            float x1 = cx - 0.5f * w, y1 = cy - 0.5f * h;   // 0.5*w exact -> fma-safe
            float4 bx = { x1, y1, x1 + w, y1 + h };
            ((float4*)gbox)[g] = bx;
            glabel[g] = ci;
        }
    } else if (lane == 0) {
        float4 zz = { 0.f, 0.f, 0.f, 0.f };
        ((float4*)gbox)[g] = zz;
        glabel[g] = -1;
    }
}

// R6's proven nms2 (FIX for R10's whale: supp built AND consumed in LDS by a
// 1024-thread block; the serial greedy wave never touches global). boxes->LDS,
// suppression words each written once (jw-rotated loop de-aliases banks),
// single-wave greedy, fused output write. IoU op-order matches reference.
__global__ __launch_bounds__(1024) void k_nms2(const float* __restrict__ gbox,
                                               const int* __restrict__ glabel,
                                               const float* __restrict__ dscore,
                                               float* __restrict__ out) {
    __shared__ float4   sbox[MAXDET];
    __shared__ int      slabel[MAXDET];
    __shared__ float    sscore[MAXDET];
    __shared__ unsigned supp[MAXDET * WORDS];
    int b = blockIdx.x;
    int tid = threadIdx.x;

    if (tid < MAXDET) {
        int g = b * MAXDET + tid;
        sbox[tid]   = ((const float4*)gbox)[g];
        slabel[tid] = glabel[g];
        sscore[tid] = dscore[g];
    }
    __syncthreads();

    // suppression bitmask: thread per 32-bit word, no atomics
    for (int T = tid; T < MAXDET * WORDS; T += 1024) {
        int i  = T / WORDS;
        int jw = T - i * WORDS;
        unsigned word = 0;
        int jbase = jw * 32;
        if (jbase + 31 > i) {
            float4 bi = sbox[i];
            int   li = slabel[i];
            float si = sscore[i];
            float ai = __fmul_rn(fmaxf(__fsub_rn(bi.z, bi.x), 0.f),
                                 fmaxf(__fsub_rn(bi.w, bi.y), 0.f));
            for (int uu = 0; uu < 32; ++uu) {
                int t = (uu + jw) & 31;       // rotation: neighbors hit different banks
                int j = jbase + t;
                if (j > i && j < MAXDET) {
                    if (slabel[j] == li && si > 0.f && sscore[j] > 0.f) {
                        float4 bj = sbox[j];
                        float xx1 = fmaxf(bi.x, bj.x);
                        float yy1 = fmaxf(bi.y, bj.y);
                        float xx2 = fminf(bi.z, bj.z);
                        float yy2 = fminf(bi.w, bj.w);
                        float iw = fmaxf(__fsub_rn(xx2, xx1), 0.f);
                        float ih = fmaxf(__fsub_rn(yy2, yy1), 0.f);
                        float inter = __fmul_rn(iw, ih);
                        float aj = __fmul_rn(fmaxf(__fsub_rn(bj.z, bj.x), 0.f),
                                             fmaxf(__fsub_rn(bj.w, bj.y), 0.f));
                        float den = __fadd_rn(__fsub_rn(__fadd_rn(ai, aj), inter), 1e-9f);
                        float iou = inter / den;     // exact IEEE div (no fast-math)
                        if (iou > NMSTH) word |= 1u << t;
                    }
                }
            }
        }
        supp[T] = word;
    }
    __syncthreads();

    // single-wave greedy: keep + nonzero-row summary in registers via ballot
    if (tid < 64) {
        int lane = tid;
        unsigned keep = 0, nzm = 0;
        #pragma unroll
        for (int s = 0; s < 5; ++s) {
            int k = s * 64 + lane;
            bool kb = (k < MAXDET) && (sscore[k] > 0.f);
            unsigned long long m = __ballot(kb);
            if (lane == 2 * s)     keep = (unsigned)m;
            if (lane == 2 * s + 1) keep = (unsigned)(m >> 32);
            unsigned nz = 0;
            if (k < MAXDET) {
                #pragma unroll
                for (int w = 0; w < WORDS; ++w) nz |= supp[k * WORDS + w];
            }
            unsigned long long mn = __ballot(nz != 0u);
            if (lane == 2 * s)     nzm = (unsigned)mn;
            if (lane == 2 * s + 1) nzm = (unsigned)(mn >> 32);
        }

        for (int i = 0; i < MAXDET; ++i) {
            int idx = i >> 5;                       // uniform
            unsigned kw = __shfl(keep, idx);
            unsigned nw = __shfl(nzm, idx);
            if (((kw & nw) >> (i & 31)) & 1u) {
                if (lane < WORDS) keep &= ~supp[i * WORDS + lane];
            }
        }

        #pragma unroll
        for (int s = 0; s < 5; ++s) {
            int k = s * 64 + lane;
            if (k < MAXDET) {
                unsigned kw = __shfl(keep, k >> 5);
                bool kp = (kw >> (k & 31)) & 1u;
                int g = b * MAXDET + k;
                float4 bx = sbox[k];
                float4 zz = { 0.f, 0.f, 0.f, 0.f };
                ((float4*)(out + O_PB))[g] = kp ? bx : zz;
                out[O_PS + g] = kp ? sscore[k] : 0.f;
                out[O_PL + g] = kp ? (float)slabel[k] : -1.f;
                out[O_PV + g] = kp ? 1.f : 0.f;
            }
        }
    }
}

extern "C" void kernel_launch(void* const* d_in, const int* in_sizes, int n_in,
                              void* d_out, int out_size, void* d_ws, size_t ws_size,
                              hipStream_t stream) {
    const float* preds = (const float*)d_in[0];
    const float* tt    = (const float*)d_in[1];
    const int*   len   = (const int*)d_in[2];
    float* out = (float*)d_out;

    char* ws = (char*)d_ws;
    float*    scores = (float*)(ws + WS_SCORE);
    float*    dscore = (float*)(ws + WS_DS);
    unsigned* didx   = (unsigned*)(ws + WS_DI);
    float*    gbox   = (float*)(ws + WS_GBOX);
    int*      glabel = (int*)(ws + WS_GLAB);

    k_score <<<SCORE_BLOCKS + NTGT_BLOCKS, 128, 0, stream>>>(preds, scores, tt, len, out);
    k_select<<<BB, 1024, 0, stream>>>(scores, dscore, didx);
    k_gather<<<(BB * MAXDET) / 8, 512, 0, stream>>>(preds, dscore, didx, gbox, glabel);
    k_nms2  <<<BB, 1024, 0, stream>>>(gbox, glabel, dscore, out);
}

// Round 12
// 89.074 us; speedup vs baseline: 1.1275x; 1.0125x over previous
//
#include <hip/hip_runtime.h>
#include <cstdint>

#define BB 16
#define NN 25200
#define NCLS 80
#define NF (5 + NCLS)
#define MAXDET 300
#define MTGT 50
#define CONF 0.8f
#define NMSTH 0.4f
#define WORDS 10
#define NBINS 2048
#define CAPALL 8192                         // all-candidate LDS buffer (+53 sigma)
#define SBUF 2048                           // post-cut sort buffer
#define APB 64                              // anchors per block in k_score
#define CHUNK_V4 (APB * NF / 4)             // 1360 float4 per block
#define SCORE_BLOCKS ((BB * NN) / APB)      // 6300
#define NTGT_BLOCKS ((BB * MTGT + 127) / 128)
#define HSTRIDE 33                          // hist row stride (bank de-alias)

// workspace byte offsets
#define WS_SCORE 0
#define WS_DS   ((size_t)BB * NN * 4)
#define WS_DI   (WS_DS + (size_t)BB * MAXDET * 4)
#define WS_GBOX (WS_DI + (size_t)BB * MAXDET * 4)
#define WS_GLAB (WS_GBOX + (size_t)BB * MAXDET * 16)

// output float offsets (return order: pb, ps, pl, pv, tb, ts, tl, tv)
#define O_PB 0
#define O_PS (BB * MAXDET * 4)
#define O_PL (O_PS + BB * MAXDET)
#define O_PV (O_PL + BB * MAXDET)
#define O_TB (O_PV + BB * MAXDET)
#define O_TS (O_TB + BB * MTGT * 4)
#define O_TL (O_TS + BB * MTGT)
#define O_TV (O_TL + BB * MTGT)

// 128-thread block stages 64 rows (21.76 KB -> 7 blocks/CU) via async
// global_load_lds width=16. Scan: 2 threads/anchor (2-way bank = free), 4 max
// accumulators (order-independent -> bit-exact), one shfl_xor, single f32 mul.
// Pinned at ~22 us ~= 137MB / 6.3TB/s HBM roofline (R8 subtraction).
__global__ __launch_bounds__(128) void k_score(const float* __restrict__ preds,
                                               float* __restrict__ scores,
                                               const float* __restrict__ tt,
                                               const int* __restrict__ len,
                                               float* __restrict__ out) {
    __shared__ float st[APB * NF];          // 21760 B
    int tid = threadIdx.x;
    int bid = blockIdx.x;

    if (bid >= SCORE_BLOCKS) {              // fused target transform
        int t = (bid - SCORE_BLOCKS) * 128 + tid;
        if (t < BB * MTGT) {
            int b = t / MTGT, m = t - b * MTGT;
            const float* row = tt + (size_t)t * 6;
            bool valid = m < len[b];
            float cx = row[0], cy = row[1], w = row[2], h = row[3];
            float x1 = cx - 0.5f * w, y1 = cy - 0.5f * h;
            float* tb = out + O_TB + (size_t)t * 4;
            tb[0] = valid ? x1 : 0.f;
            tb[1] = valid ? y1 : 0.f;
            tb[2] = valid ? (x1 + w) : 0.f;
            tb[3] = valid ? (y1 + h) : 0.f;
            out[O_TS + t] = valid ? row[4] : 0.f;
            out[O_TL + t] = valid ? (float)(int)row[5] : -1.f;
            out[O_TV + t] = valid ? 1.f : 0.f;
        }
        return;
    }

    int w = tid >> 6;                       // wave id (uniform per wave)
    const float4* src = (const float4*)(preds + (size_t)bid * (APB * NF));
    #pragma unroll
    for (int i = 0; i < 11; ++i) {
        int idx = i * 128 + tid;            // global float4 index, contiguous
        if (idx < CHUNK_V4) {
            __builtin_amdgcn_global_load_lds(
                (const __attribute__((address_space(1))) void*)(src + idx),
                (__attribute__((address_space(3))) void*)(st + (i * 128 + w * 64) * 4),
                16, 0, 0);
        }
    }
    __syncthreads();                        // drains vmcnt -> LDS valid

    int a = tid >> 1, h = tid & 1;          // anchor, half
    const float* cls = st + a * NF + 5 + h * 40;
    float m0 = cls[0], m1 = cls[1], m2 = cls[2], m3 = cls[3];
    #pragma unroll
    for (int f = 4; f < 40; f += 4) {
        m0 = fmaxf(m0, cls[f]);     m1 = fmaxf(m1, cls[f + 1]);
        m2 = fmaxf(m2, cls[f + 2]); m3 = fmaxf(m3, cls[f + 3]);
    }
    float m = fmaxf(fmaxf(m0, m1), fmaxf(m2, m3));
    m = fmaxf(m, __shfl_xor(m, 1));
    if (h == 0) scores[bid * APB + a] = st[a * NF + 4] * m;  // single mul, bit-exact
}

// One block per batch. R11 post-mortem: bulk LDS staging cost +24us -> reverted
// to streaming global reads, but SINGLE-PASS float4 scan (7 iters, was 2x25):
// builds histogram AND compacts all >CONF candidates to LDS skall in one pass;
// cut-bin filter then reads LDS. Coarse bins only SELECT (cut-bin ties all
// included); bitonic sort on exact 64-bit keys ORDERS -> bit-identical to full
// sort (JAX top_k tie semantics via inverted index in low bits).
__global__ __launch_bounds__(1024) void k_select(const float* __restrict__ scores,
                                                 float* __restrict__ dscore,
                                                 unsigned* __restrict__ didx) {
    __shared__ unsigned long long skall[CAPALL];  // 65536 B
    __shared__ unsigned long long sk[SBUF];       // 16384 B
    __shared__ int hist[64 * HSTRIDE];            // 8448 B  (~90.5 KB total)
    __shared__ int lcnt, lcnt2, scut;
    int b = blockIdx.x;
    int tid = threadIdx.x;
    int lane = tid & 63;

    if (tid == 0) { lcnt = 0; lcnt2 = 0; }
    for (int i = tid; i < 64 * HSTRIDE; i += 1024) hist[i] = 0;
    for (int i = tid; i < SBUF; i += 1024) sk[i] = 0ull;   // pad keys for sort
    __syncthreads();

    // phase A: ONE vectorized global pass: hist + compact-all (>CONF).
    // scores in (0.8,1.0] share one exponent region -> (u-0x3F400000)>>12
    // is monotone in float order. Padded uniform bound keeps ballots full-wave.
    const float4* src4 = (const float4*)(scores + (size_t)b * NN);
    for (int v = tid; v < 7168; v += 1024) {            // NN/4 = 6300
        float4 s4 = make_float4(0.f, 0.f, 0.f, 0.f);
        if (v < NN / 4) s4 = src4[v];
        #pragma unroll
        for (int c = 0; c < 4; ++c) {
            float s = (c == 0) ? s4.x : (c == 1) ? s4.y : (c == 2) ? s4.z : s4.w;
            bool pass = s > CONF;
            unsigned u = __float_as_uint(s);
            if (pass) {
                int bin = (int)((u - 0x3F400000u) >> 12);
                bin = bin < 0 ? 0 : (bin > NBINS - 1 ? NBINS - 1 : bin);
                atomicAdd(&hist[(bin >> 5) * HSTRIDE + (bin & 31)], 1);
            }
            unsigned long long mask = __ballot(pass);
            int wcnt = __popcll(mask);
            int bs = 0;
            if (lane == 0 && wcnt) bs = atomicAdd(&lcnt, wcnt);
            bs = __shfl(bs, 0);
            if (pass) {
                int pos = bs + __popcll(mask & ((1ull << lane) - 1ull));
                if (pos < CAPALL)
                    skall[pos] = ((unsigned long long)u << 32) |
                                 (unsigned long long)(0xFFFFFFFFu - (unsigned)(4 * v + c));
            }
        }
    }
    __syncthreads();

    // phase B: find cut bin (largest bin with suffix-count >= 300), one wave
    if (tid < 64) {
        int sb = 0;
        #pragma unroll
        for (int k = 0; k < 32; ++k) sb += hist[lane * HSTRIDE + k];
        int cum = sb;                              // suffix sum over 64 superbins
        #pragma unroll
        for (int d = 1; d < 64; d <<= 1) {
            int o = __shfl_down(cum, d);
            if (lane + d < 64) cum += o;
        }
        unsigned long long m = __ballot(cum >= MAXDET);
        int cutbin = 0;
        if (m) {
            int cutS = 63 - __clzll(m);
            int tail = (cutS < 63) ? __shfl(cum, cutS + 1) : 0;
            int hh = (lane < 32) ? hist[cutS * HSTRIDE + lane] : 0;
            int c2 = hh;                           // suffix sum within superbin
            #pragma unroll
            for (int d = 1; d < 32; d <<= 1) {
                int o = __shfl_down(c2, d);
                if (lane + d < 32) c2 += o;
            }
            c2 += tail;
            unsigned long long m2 = __ballot(lane < 32 && c2 >= MAXDET);
            int cutL = 63 - __clzll(m2);           // m2 != 0 guaranteed
            cutbin = cutS * 32 + cutL;
        }
        if (lane == 0) scut = cutbin;
    }
    __syncthreads();
    int cutbin = scut;

    // phase C: compact bin >= cutbin FROM LDS skall (wave-aggregated)
    int M = lcnt; if (M > CAPALL) M = CAPALL;
    for (int i = tid; i < ((M + 1023) & ~1023); i += 1024) {
        bool pass = false;
        unsigned long long key = 0ull;
        if (i < M) {
            key = skall[i];
            unsigned u = (unsigned)(key >> 32);
            int bin = (int)((u - 0x3F400000u) >> 12);
            bin = bin < 0 ? 0 : (bin > NBINS - 1 ? NBINS - 1 : bin);
            pass = bin >= cutbin;
        }
        unsigned long long mask = __ballot(pass);
        int wcnt = __popcll(mask);
        int bs = 0;
        if (lane == 0 && wcnt) bs = atomicAdd(&lcnt2, wcnt);
        bs = __shfl(bs, 0);
        if (pass) {
            int pos = bs + __popcll(mask & ((1ull << lane) - 1ull));
            if (pos < SBUF) sk[pos] = key;
        }
    }
    __syncthreads();

    // phase D: bitonic sort P in {512,1024,2048} elements, descending (proven)
    int M2 = lcnt2; if (M2 > SBUF) M2 = SBUF;
    unsigned P = 512;
    while ((int)P < M2) P <<= 1;

    for (unsigned k = 2; k <= P; k <<= 1) {
        for (unsigned j = k >> 1; j > 0; j >>= 1) {
            __syncthreads();
            for (unsigned i = tid; i < P; i += 1024) {
                unsigned ixj = i ^ j;
                if (ixj > i) {
                    unsigned long long a = sk[i], d = sk[ixj];
                    bool desc = ((i & k) == 0);
                    if (desc ? (a < d) : (a > d)) { sk[i] = d; sk[ixj] = a; }
                }
            }
        }
    }
    __syncthreads();
    for (int q = tid; q < MAXDET; q += 1024) {
        unsigned long long key = sk[q];
        unsigned sbits = (unsigned)(key >> 32);
        dscore[b * MAXDET + q] = __uint_as_float(sbits);
        didx[b * MAXDET + q]   = sbits ? (0xFFFFFFFFu - (unsigned)(key & 0xFFFFFFFFu)) : 0u;
    }
}

// wave per detection (600 blocks -> all rows fetched in parallel): gather row,
// first-occurrence argmax, box -> gbox/glabel
__global__ __launch_bounds__(512) void k_gather(const float* __restrict__ preds,
                                                const float* __restrict__ dscore,
                                                const unsigned* __restrict__ didx,
                                                float* __restrict__ gbox,
                                                int* __restrict__ glabel) {
    int g    = blockIdx.x * 8 + (threadIdx.x >> 6);   // b*MAXDET + k
    int lane = threadIdx.x & 63;
    float sc = dscore[g];
    if (sc > 0.f) {
        int b = g / MAXDET;
        int idx = (int)didx[g];
        const float* row = preds + ((size_t)b * NN + (size_t)idx) * NF;
        float v = row[5 + lane]; int ci = lane;
        if (lane < 16) { float v2 = row[69 + lane]; if (v2 > v) { v = v2; ci = lane + 64; } }
        #pragma unroll
        for (int m = 32; m >= 1; m >>= 1) {
            float ov = __shfl_xor(v, m);
            int   oi = __shfl_xor(ci, m);
            if (ov > v || (ov == v && oi < ci)) { v = ov; ci = oi; }
        }
        if (lane == 0) {
            float cx = row[0], cy = row[1], w = row[2], h = row[3];
            float x1 = cx - 0.5f * w, y1 = cy - 0.5f * h;   // 0.5*w exact -> fma-safe
            float4 bx = { x1, y1, x1 + w, y1 + h };
            ((float4*)gbox)[g] = bx;
            glabel[g] = ci;
        }
    } else if (lane == 0) {
        float4 zz = { 0.f, 0.f, 0.f, 0.f };
        ((float4*)gbox)[g] = zz;
        glabel[g] = -1;
    }
}

// Proven nms2: supp built AND consumed in LDS (serial greedy wave never touches
// global). boxes->LDS, suppression words each written once (jw-rotated loop
// de-aliases banks), single-wave greedy, fused output. IoU op-order = reference.
__global__ __launch_bounds__(1024) void k_nms2(const float* __restrict__ gbox,
                                               const int* __restrict__ glabel,
                                               const float* __restrict__ dscore,
                                               float* __restrict__ out) {
    __shared__ float4   sbox[MAXDET];
    __shared__ int      slabel[MAXDET];
    __shared__ float    sscore[MAXDET];
    __shared__ unsigned supp[MAXDET * WORDS];
    int b = blockIdx.x;
    int tid = threadIdx.x;

    if (tid < MAXDET) {
        int g = b * MAXDET + tid;
        sbox[tid]   = ((const float4*)gbox)[g];
        slabel[tid] = glabel[g];
        sscore[tid] = dscore[g];
    }
    __syncthreads();

    for (int T = tid; T < MAXDET * WORDS; T += 1024) {
        int i  = T / WORDS;
        int jw = T - i * WORDS;
        unsigned word = 0;
        int jbase = jw * 32;
        if (jbase + 31 > i) {
            float4 bi = sbox[i];
            int   li = slabel[i];
            float si = sscore[i];
            float ai = __fmul_rn(fmaxf(__fsub_rn(bi.z, bi.x), 0.f),
                                 fmaxf(__fsub_rn(bi.w, bi.y), 0.f));
            for (int uu = 0; uu < 32; ++uu) {
                int t = (uu + jw) & 31;       // rotation: neighbors hit different banks
                int j = jbase + t;
                if (j > i && j < MAXDET) {
                    if (slabel[j] == li && si > 0.f && sscore[j] > 0.f) {
                        float4 bj = sbox[j];
                        float xx1 = fmaxf(bi.x, bj.x);
                        float yy1 = fmaxf(bi.y, bj.y);
                        float xx2 = fminf(bi.z, bj.z);
                        float yy2 = fminf(bi.w, bj.w);
                        float iw = fmaxf(__fsub_rn(xx2, xx1), 0.f);
                        float ih = fmaxf(__fsub_rn(yy2, yy1), 0.f);
                        float inter = __fmul_rn(iw, ih);
                        float aj = __fmul_rn(fmaxf(__fsub_rn(bj.z, bj.x), 0.f),
                                             fmaxf(__fsub_rn(bj.w, bj.y), 0.f));
                        float den = __fadd_rn(__fsub_rn(__fadd_rn(ai, aj), inter), 1e-9f);
                        float iou = inter / den;     // exact IEEE div (no fast-math)
                        if (iou > NMSTH) word |= 1u << t;
                    }
                }
            }
        }
        supp[T] = word;
    }
    __syncthreads();

    if (tid < 64) {
        int lane = tid;
        unsigned keep = 0, nzm = 0;
        #pragma unroll
        for (int s = 0; s < 5; ++s) {
            int k = s * 64 + lane;
            bool kb = (k < MAXDET) && (sscore[k] > 0.f);
            unsigned long long m = __ballot(kb);
            if (lane == 2 * s)     keep = (unsigned)m;
            if (lane == 2 * s + 1) keep = (unsigned)(m >> 32);
            unsigned nz = 0;
            if (k < MAXDET) {
                #pragma unroll
                for (int w = 0; w < WORDS; ++w) nz |= supp[k * WORDS + w];
            }
            unsigned long long mn = __ballot(nz != 0u);
            if (lane == 2 * s)     nzm = (unsigned)mn;
            if (lane == 2 * s + 1) nzm = (unsigned)(mn >> 32);
        }

        for (int i = 0; i < MAXDET; ++i) {
            int idx = i >> 5;                       // uniform
            unsigned kw = __shfl(keep, idx);
            unsigned nw = __shfl(nzm, idx);
            if (((kw & nw) >> (i & 31)) & 1u) {
                if (lane < WORDS) keep &= ~supp[i * WORDS + lane];
            }
        }

        #pragma unroll
        for (int s = 0; s < 5; ++s) {
            int k = s * 64 + lane;
            if (k < MAXDET) {
                unsigned kw = __shfl(keep, k >> 5);
                bool kp = (kw >> (k & 31)) & 1u;
                int g = b * MAXDET + k;
                float4 bx = sbox[k];
                float4 zz = { 0.f, 0.f, 0.f, 0.f };
                ((float4*)(out + O_PB))[g] = kp ? bx : zz;
                out[O_PS + g] = kp ? sscore[k] : 0.f;
                out[O_PL + g] = kp ? (float)slabel[k] : -1.f;
                out[O_PV + g] = kp ? 1.f : 0.f;
            }
        }
    }
}

extern "C" void kernel_launch(void* const* d_in, const int* in_sizes, int n_in,
                              void* d_out, int out_size, void* d_ws, size_t ws_size,
                              hipStream_t stream) {
    const float* preds = (const float*)d_in[0];
    const float* tt    = (const float*)d_in[1];
    const int*   len   = (const int*)d_in[2];
    float* out = (float*)d_out;

    char* ws = (char*)d_ws;
    float*    scores = (float*)(ws + WS_SCORE);
    float*    dscore = (float*)(ws + WS_DS);
    unsigned* didx   = (unsigned*)(ws + WS_DI);
    float*    gbox   = (float*)(ws + WS_GBOX);
    int*      glabel = (int*)(ws + WS_GLAB);

    k_score <<<SCORE_BLOCKS + NTGT_BLOCKS, 128, 0, stream>>>(preds, scores, tt, len, out);
    k_select<<<BB, 1024, 0, stream>>>(scores, dscore, didx);
    k_gather<<<(BB * MAXDET) / 8, 512, 0, stream>>>(preds, dscore, didx, gbox, glabel);
    k_nms2  <<<BB, 1024, 0, stream>>>(gbox, glabel, dscore, out);
}